// Round 1
// baseline (872.066 us; speedup 1.0000x reference)
//
#include <hip/hip_runtime.h>
#include <math.h>

typedef _Float16 half8  __attribute__((ext_vector_type(8)));
typedef _Float16 half2v __attribute__((ext_vector_type(2)));
typedef float    floatx4 __attribute__((ext_vector_type(4)));

// wave-local LDS fence: all LDS traffic is intra-wave (one wave per block),
// DS ops complete in order per wave -> s_waitcnt lgkmcnt(0) is a full fence.
#define LGKM_FENCE() asm volatile("s_waitcnt lgkmcnt(0)" ::: "memory")

// ---------------------------------------------------------------------------
// K1: segment boundaries. seg_ids sorted, every id in [0,G) present.
// ---------------------------------------------------------------------------
__global__ void seg_bounds_kernel(const int* __restrict__ seg,
                                  int* __restrict__ seg_start, int N, int G) {
    int i = blockIdx.x * 256 + threadIdx.x;
    if (i >= N) return;
    int s = seg[i];
    if (i == 0 || s != seg[i - 1]) seg_start[s] = i;
    if (i == N - 1) seg_start[G] = N;
}

__device__ inline half8 pack8(float4 a, float4 b) {
    half8 r;
    r[0] = (_Float16)a.x; r[1] = (_Float16)a.y; r[2] = (_Float16)a.z; r[3] = (_Float16)a.w;
    r[4] = (_Float16)b.x; r[5] = (_Float16)b.y; r[6] = (_Float16)b.z; r[7] = (_Float16)b.w;
    return r;
}

// ---------------------------------------------------------------------------
// K2: fused keys-GEMM + q-GEMM + per-segment softmax + weighted sum.
// ONE WAVE PER BLOCK (64 threads), 16 consecutive segments per wave.
// Softmax restructured: lane m owns segment g0+m's running max (tree-max per
// tile, one rescale per tile); the per-row loop carries only independent FMA
// chains (acc0/acc1/d_acc), exp is off the loop-carried path.
// MFMA 16x16x32 f16 layouts (verified m89/m120):
//   A[m=lane&15][k=quad*8+j], B[n=lane&15][k=quad*8+j], C: col=lane&15,
//   row=quad*4+reg.
// ---------------------------------------------------------------------------
__global__ __launch_bounds__(64, 2) void fused_attn_kernel(
    const float* __restrict__ emb, const int* __restrict__ seg_start,
    const float* __restrict__ Wq, const float* __restrict__ bq,
    const float* __restrict__ Wk, const float* __restrict__ bk,
    float* __restrict__ out)
{
    __shared__ alignas(16) _Float16 keys_lds[16][136];  // stride 136h = 272B
    __shared__ alignas(16) _Float16 q_lds[16][136];
    __shared__ alignas(16) float    L_lds[16];

    const int lane = threadIdx.x;      // 0..63 (one wave)
    const int m    = lane & 15;
    const int quad = lane >> 4;

    const int g0 = blockIdx.x * 16;    // first of this wave's 16 segments
    // per-lane bounds of "owned" segment g0+m (replicated across quads)
    const int lo = seg_start[g0 + m];
    const int hi = seg_start[g0 + m + 1];
    const int s0 = __shfl(lo, 0);
    const int e0 = __shfl(hi, 15);

    // bk for this lane's column slots (dim = 16c + m)
    float bkv[8];
#pragma unroll
    for (int c = 0; c < 8; ++c) bkv[c] = bk[16 * c + m];

    // -------- phase 1: q for the 16 segments (one MFMA col pass) ----------
    {
        long qrow = (long)hi - 1;                  // last row of segment g0+m
        half8 aq[4];
#pragma unroll
        for (int kq = 0; kq < 4; ++kq) {
            const float4* p = (const float4*)(emb + qrow * 128 + kq * 32 + quad * 8);
            aq[kq] = pack8(p[0], p[1]);
        }
#pragma unroll
        for (int c = 0; c < 8; ++c) {
            float bqc = bq[16 * c + m];
            floatx4 acc = {bqc, bqc, bqc, bqc};
#pragma unroll
            for (int kq = 0; kq < 4; ++kq) {
                const float4* wp = (const float4*)(Wq + (16 * c + m) * 128 + kq * 32 + quad * 8);
                half8 bf = pack8(wp[0], wp[1]);
                acc = __builtin_amdgcn_mfma_f32_16x16x32_f16(aq[kq], bf, acc, 0, 0, 0);
            }
#pragma unroll
            for (int r = 0; r < 4; ++r)
                q_lds[quad * 4 + r][16 * c + m] = (_Float16)acc[r];
        }
    }
    LGKM_FENCE();   // publish q_lds to the wave

    // q as B-fragments, kept in registers for the whole main loop
    half8 qf[4];
#pragma unroll
    for (int kq = 0; kq < 4; ++kq)
        qf[kq] = *(const half8*)&q_lds[m][kq * 32 + quad * 8];

    // -------- phase 2: all of Wk into registers (f16 B-fragments) ---------
    half8 wkf[8][4];
#pragma unroll
    for (int c = 0; c < 8; ++c)
#pragma unroll
        for (int kq = 0; kq < 4; ++kq) {
            const float4* wp = (const float4*)(Wk + (16 * c + m) * 128 + kq * 32 + quad * 8);
            wkf[c][kq] = pack8(wp[0], wp[1]);
        }

    const int nt = (e0 - s0 + 15) >> 4;

    // preload tile 0 raw (software pipeline stage)
    float4 pre[8];
    {
        long prow = (long)min(s0 + m, e0 - 1);
#pragma unroll
        for (int kq = 0; kq < 4; ++kq) {
            const float4* p = (const float4*)(emb + prow * 128 + kq * 32 + quad * 8);
            pre[2 * kq] = p[0]; pre[2 * kq + 1] = p[1];
        }
    }

    // current-segment state (scalar, segments arrive sorted)
    int   g = g0;
    int   cur_end = __shfl(hi, 0);
    float M_run = -INFINITY;   // owner-lane running max for segment g0+m
    float M_cur = 0.f;         // current segment's merged max (set per tile)
    float d_acc = 0.f, acc0 = 0.f, acc1 = 0.f;

    for (int tt = 0; tt < nt; ++tt) {
        const int t   = s0 + tt * 16;
        const int cnt = min(16, e0 - t);

        // consume prefetched raw -> A fragments
        half8 ak[4];
#pragma unroll
        for (int kq = 0; kq < 4; ++kq)
            ak[kq] = pack8(pre[2 * kq], pre[2 * kq + 1]);

        // prefetch next tile (overlaps MFMA + softmax below)
        if (tt + 1 < nt) {
            long nrow = (long)min(t + 16 + m, e0 - 1);
#pragma unroll
            for (int kq = 0; kq < 4; ++kq) {
                const float4* p = (const float4*)(emb + nrow * 128 + kq * 32 + quad * 8);
                pre[2 * kq] = p[0]; pre[2 * kq + 1] = p[1];
            }
        }

        // keys = emb @ Wk^T + bk (bias folded into acc init)
#pragma unroll
        for (int c = 0; c < 8; ++c) {
            floatx4 acc = {bkv[c], bkv[c], bkv[c], bkv[c]};
#pragma unroll
            for (int kq = 0; kq < 4; ++kq)
                acc = __builtin_amdgcn_mfma_f32_16x16x32_f16(ak[kq], wkf[c][kq], acc, 0, 0, 0);
#pragma unroll
            for (int r = 0; r < 4; ++r)
                keys_lds[quad * 4 + r][16 * c + m] = (_Float16)acc[r];
        }
        LGKM_FENCE();   // keys_lds visible to the wave

        // logits: L[row][s] = keys[row] . q[s] via one MFMA col-tile
        floatx4 lacc = {0.f, 0.f, 0.f, 0.f};
#pragma unroll
        for (int kq = 0; kq < 4; ++kq) {
            half8 af = *(const half8*)&keys_lds[m][kq * 32 + quad * 8];
            lacc = __builtin_amdgcn_mfma_f32_16x16x32_f16(af, qf[kq], lacc, 0, 0, 0);
        }
        // extract L[row][seg(row)]: the lane whose owned range contains the
        // row writes (exactly one lane per row; no segment search needed)
#pragma unroll
        for (int r = 0; r < 4; ++r) {
            int rowc = t + quad * 4 + r;
            if (rowc >= lo && rowc < hi) L_lds[quad * 4 + r] = lacc[r];
        }
        LGKM_FENCE();   // L_lds visible

        // batch all LDS reads, then pure register work
        float lg[16];
#pragma unroll
        for (int i = 0; i < 4; ++i) {
            float4 v = *(const float4*)&L_lds[4 * i];   // broadcast reads
            lg[4 * i] = v.x; lg[4 * i + 1] = v.y; lg[4 * i + 2] = v.z; lg[4 * i + 3] = v.w;
        }
        half2v kv[16];
#pragma unroll
        for (int r = 0; r < 16; ++r)
            kv[r] = *(const half2v*)&keys_lds[r][2 * lane];

        // owner-lane: tile-local max of owned segment (masked depth-4 tree),
        // merge into running max, derive one rescale factor for this tile
        float tv[16];
#pragma unroll
        for (int r = 0; r < 16; ++r) {
            int row = t + r;
            tv[r] = (row >= lo && row < hi) ? lg[r] : -INFINITY;
        }
#pragma unroll
        for (int s = 8; s > 0; s >>= 1)
#pragma unroll
            for (int r = 0; r < s; ++r) tv[r] = fmaxf(tv[r], tv[r + s]);
        float M_new = fmaxf(M_run, tv[0]);
        // guard: before a segment's first row, M_run = -inf and -inf-(-inf)=NaN
        float sc = (M_run == -INFINITY) ? 0.f : __expf(M_run - M_new);
        M_run = M_new;

        // rescale current segment's accumulators once per tile
        float sc_c = __shfl(sc, g - g0);
        M_cur      = __shfl(M_new, g - g0);
        acc0 *= sc_c; acc1 *= sc_c; d_acc *= sc_c;

        // serial row phase: only independent FMA chains are loop-carried
#pragma unroll
        for (int rl = 0; rl < 16; ++rl) {
            if (rl < cnt) {                      // wave-uniform guard
                int row = t + rl;
                while (row >= cur_end) {         // wave-uniform boundary
                    float inv = 1.0f / d_acc;
                    float2 o; o.x = acc0 * inv; o.y = acc1 * inv;
                    *(float2*)(out + (long)g * 128 + 2 * lane) = o;
                    ++g;
                    cur_end = __shfl(hi, g - g0);
                    M_cur   = __shfl(M_new, g - g0);
                    acc0 = 0.f; acc1 = 0.f; d_acc = 0.f;
                }
                float e = __expf(lg[rl] - M_cur);   // off the carried chain
                acc0  += e * (float)kv[rl][0];
                acc1  += e * (float)kv[rl][1];
                d_acc += e;
            }
        }
    }
    // finalize the wave's last segment
    {
        float inv = 1.0f / d_acc;
        float2 o; o.x = acc0 * inv; o.y = acc1 * inv;
        *(float2*)(out + (long)g * 128 + 2 * lane) = o;
    }
}

// ---------------------------------------------------------------------------
extern "C" void kernel_launch(void* const* d_in, const int* in_sizes, int n_in,
                              void* d_out, int out_size, void* d_ws, size_t ws_size,
                              hipStream_t stream) {
    const float* emb = (const float*)d_in[0];
    const int*   seg = (const int*)d_in[1];
    const float* Wq  = (const float*)d_in[2];
    const float* bq  = (const float*)d_in[3];
    const float* Wk  = (const float*)d_in[4];
    const float* bk  = (const float*)d_in[5];
    float* out = (float*)d_out;

    const int N = in_sizes[1];          // number of rows / seg ids
    const int G = out_size / 128;       // number of segments

    int* seg_start = (int*)d_ws;        // (G+1) ints

    seg_bounds_kernel<<<(N + 255) / 256, 256, 0, stream>>>(seg, seg_start, N, G);
    // G = 100000 divisible by 16 (16 segments per wave, 1 wave per block)
    fused_attn_kernel<<<G / 16, 64, 0, stream>>>(emb, seg_start, Wq, bq, Wk, bk, out);
}

// Round 2
// 860.602 us; speedup vs baseline: 1.0133x; 1.0133x over previous
//
#include <hip/hip_runtime.h>
#include <math.h>

typedef _Float16 half8  __attribute__((ext_vector_type(8)));
typedef _Float16 half2v __attribute__((ext_vector_type(2)));
typedef float    floatx4 __attribute__((ext_vector_type(4)));

// wave-local LDS fence: all LDS traffic is intra-wave (one wave per block),
// DS ops complete in order per wave -> s_waitcnt lgkmcnt(0) is a full fence.
#define LGKM_FENCE() asm volatile("s_waitcnt lgkmcnt(0)" ::: "memory")

// ---------------------------------------------------------------------------
// K1: segment boundaries. seg_ids sorted, every id in [0,G) present.
// ---------------------------------------------------------------------------
__global__ void seg_bounds_kernel(const int* __restrict__ seg,
                                  int* __restrict__ seg_start, int N, int G) {
    int i = blockIdx.x * 256 + threadIdx.x;
    if (i >= N) return;
    int s = seg[i];
    if (i == 0 || s != seg[i - 1]) seg_start[s] = i;
    if (i == N - 1) seg_start[G] = N;
}

__device__ inline half8 pack8(float4 a, float4 b) {
    half8 r;
    r[0] = (_Float16)a.x; r[1] = (_Float16)a.y; r[2] = (_Float16)a.z; r[3] = (_Float16)a.w;
    r[4] = (_Float16)b.x; r[5] = (_Float16)b.y; r[6] = (_Float16)b.z; r[7] = (_Float16)b.w;
    return r;
}

// ---------------------------------------------------------------------------
// K2: fused keys-GEMM + q-GEMM + per-segment softmax + weighted sum.
// ONE WAVE PER BLOCK (64 threads), 8 consecutive segments per wave.
// Register budget is the first-class concern: round-1 spilled (~62 MB excess
// scratch writes) at VGPR cap 128. Here: no tv[] tree (masked fmax chain
// instead), launch_bounds(64,1) so the allocator takes ~160 regs instead of
// spilling.
// MFMA 16x16x32 f16 layouts (verified m89/m120):
//   A[m=lane&15][k=quad*8+j], B[n=lane&15][k=quad*8+j], C: col=lane&15,
//   row=quad*4+reg.
// ---------------------------------------------------------------------------
__global__ __launch_bounds__(64, 1) void fused_attn_kernel(
    const float* __restrict__ emb, const int* __restrict__ seg_start,
    const float* __restrict__ Wq, const float* __restrict__ bq,
    const float* __restrict__ Wk, const float* __restrict__ bk,
    float* __restrict__ out)
{
    __shared__ alignas(16) _Float16 keys_lds[16][136];  // stride 136h = 272B
    __shared__ alignas(16) _Float16 q_lds[8][136];
    __shared__ alignas(16) float    L_lds[16];

    const int lane = threadIdx.x;      // 0..63 (one wave)
    const int m    = lane & 15;
    const int quad = lane >> 4;

    const int g0 = blockIdx.x * 8;     // first of this wave's 8 segments
    // per-lane bounds of "owned" segment g0+(m&7); lanes 8..15 duplicate
    const int lo = seg_start[g0 + (m & 7)];
    const int hi = seg_start[g0 + (m & 7) + 1];
    const int s0 = __shfl(lo, 0);
    const int e0 = __shfl(hi, 7);      // end of last owned segment

    // bk for this lane's column slots (dim = 16c + m)
    float bkv[8];
#pragma unroll
    for (int c = 0; c < 8; ++c) bkv[c] = bk[16 * c + m];

    // -------- phase 1: q for the 8 segments (one MFMA col pass) -----------
    {
        long qrow = (long)hi - 1;      // last row of owned segment (dup m>=8)
        half8 aq[4];
#pragma unroll
        for (int kq = 0; kq < 4; ++kq) {
            const float4* p = (const float4*)(emb + qrow * 128 + kq * 32 + quad * 8);
            aq[kq] = pack8(p[0], p[1]);
        }
#pragma unroll
        for (int c = 0; c < 8; ++c) {
            float bqc = bq[16 * c + m];
            floatx4 acc = {bqc, bqc, bqc, bqc};
#pragma unroll
            for (int kq = 0; kq < 4; ++kq) {
                const float4* wp = (const float4*)(Wq + (16 * c + m) * 128 + kq * 32 + quad * 8);
                half8 bf = pack8(wp[0], wp[1]);
                acc = __builtin_amdgcn_mfma_f32_16x16x32_f16(aq[kq], bf, acc, 0, 0, 0);
            }
            if (quad < 2) {                            // rows 0..7 = segments
#pragma unroll
                for (int r = 0; r < 4; ++r)
                    q_lds[quad * 4 + r][16 * c + m] = (_Float16)acc[r];
            }
        }
    }
    LGKM_FENCE();   // publish q_lds to the wave

    // q as B-fragments, kept in registers for the whole main loop
    half8 qf[4];
#pragma unroll
    for (int kq = 0; kq < 4; ++kq)
        qf[kq] = *(const half8*)&q_lds[m & 7][kq * 32 + quad * 8];

    // -------- phase 2: all of Wk into registers (f16 B-fragments) ---------
    half8 wkf[8][4];
#pragma unroll
    for (int c = 0; c < 8; ++c)
#pragma unroll
        for (int kq = 0; kq < 4; ++kq) {
            const float4* wp = (const float4*)(Wk + (16 * c + m) * 128 + kq * 32 + quad * 8);
            wkf[c][kq] = pack8(wp[0], wp[1]);
        }

    const int nt = (e0 - s0 + 15) >> 4;

    // preload tile 0 raw (software pipeline stage)
    float4 pre[8];
    {
        long prow = (long)min(s0 + m, e0 - 1);
#pragma unroll
        for (int kq = 0; kq < 4; ++kq) {
            const float4* p = (const float4*)(emb + prow * 128 + kq * 32 + quad * 8);
            pre[2 * kq] = p[0]; pre[2 * kq + 1] = p[1];
        }
    }

    // current-segment state (scalar, segments arrive sorted)
    int   g = g0;
    int   cur_end = __shfl(hi, 0);
    float M_run = -INFINITY;   // owner-lane running max for segment g0+(m&7)
    float M_cur = 0.f;         // current segment's merged max (set per tile)
    float d_acc = 0.f, acc0 = 0.f, acc1 = 0.f;

    for (int tt = 0; tt < nt; ++tt) {
        const int t   = s0 + tt * 16;
        const int cnt = min(16, e0 - t);

        // consume prefetched raw -> A fragments
        half8 ak[4];
#pragma unroll
        for (int kq = 0; kq < 4; ++kq)
            ak[kq] = pack8(pre[2 * kq], pre[2 * kq + 1]);

        // prefetch next tile (overlaps MFMA + softmax below)
        if (tt + 1 < nt) {
            long nrow = (long)min(t + 16 + m, e0 - 1);
#pragma unroll
            for (int kq = 0; kq < 4; ++kq) {
                const float4* p = (const float4*)(emb + nrow * 128 + kq * 32 + quad * 8);
                pre[2 * kq] = p[0]; pre[2 * kq + 1] = p[1];
            }
        }

        // keys = emb @ Wk^T + bk (bias folded into acc init)
#pragma unroll
        for (int c = 0; c < 8; ++c) {
            floatx4 acc = {bkv[c], bkv[c], bkv[c], bkv[c]};
#pragma unroll
            for (int kq = 0; kq < 4; ++kq)
                acc = __builtin_amdgcn_mfma_f32_16x16x32_f16(ak[kq], wkf[c][kq], acc, 0, 0, 0);
#pragma unroll
            for (int r = 0; r < 4; ++r)
                keys_lds[quad * 4 + r][16 * c + m] = (_Float16)acc[r];
        }
        LGKM_FENCE();   // keys_lds visible to the wave

        // logits: L[row][s] = keys[row] . q[s] via one MFMA col-tile
        floatx4 lacc = {0.f, 0.f, 0.f, 0.f};
#pragma unroll
        for (int kq = 0; kq < 4; ++kq) {
            half8 af = *(const half8*)&keys_lds[m][kq * 32 + quad * 8];
            lacc = __builtin_amdgcn_mfma_f32_16x16x32_f16(af, qf[kq], lacc, 0, 0, 0);
        }
        // extract L[row][seg(row)]: the owner lane (m<8, owned range contains
        // the row) writes — exactly one lane per valid row
#pragma unroll
        for (int r = 0; r < 4; ++r) {
            int rowc = t + quad * 4 + r;
            if (m < 8 && rowc >= lo && rowc < hi) L_lds[quad * 4 + r] = lacc[r];
        }
        LGKM_FENCE();   // L_lds visible

        // batch all LDS reads, then pure register work
        float lg[16];
#pragma unroll
        for (int i = 0; i < 4; ++i) {
            float4 v = *(const float4*)&L_lds[4 * i];   // broadcast reads
            lg[4 * i] = v.x; lg[4 * i + 1] = v.y; lg[4 * i + 2] = v.z; lg[4 * i + 3] = v.w;
        }
        half2v kv[16];
#pragma unroll
        for (int r = 0; r < 16; ++r)
            kv[r] = *(const half2v*)&keys_lds[r][2 * lane];

        // owner-lane tile max of owned segment: masked sequential fmax chain
        // (no register array; once per tile, off the per-row path)
        float tm = -INFINITY;
#pragma unroll
        for (int r = 0; r < 16; ++r) {
            int row = t + r;
            tm = fmaxf(tm, (row >= lo && row < hi) ? lg[r] : -INFINITY);
        }
        float M_new = fmaxf(M_run, tm);
        // guard: before a segment's first row, M_run = -inf and -inf-(-inf)=NaN
        float sc = (M_run == -INFINITY) ? 0.f : __expf(M_run - M_new);
        M_run = M_new;

        // rescale current segment's accumulators once per tile
        float sc_c = __shfl(sc, g - g0);
        M_cur      = __shfl(M_new, g - g0);
        acc0 *= sc_c; acc1 *= sc_c; d_acc *= sc_c;

        // serial row phase: only independent FMA chains are loop-carried
#pragma unroll
        for (int rl = 0; rl < 16; ++rl) {
            if (rl < cnt) {                      // wave-uniform guard
                int row = t + rl;
                while (row >= cur_end) {         // wave-uniform boundary
                    float inv = 1.0f / d_acc;
                    float2 o; o.x = acc0 * inv; o.y = acc1 * inv;
                    *(float2*)(out + (long)g * 128 + 2 * lane) = o;
                    ++g;
                    cur_end = __shfl(hi, g - g0);
                    M_cur   = __shfl(M_new, g - g0);
                    acc0 = 0.f; acc1 = 0.f; d_acc = 0.f;
                }
                float e = __expf(lg[rl] - M_cur);   // off the carried chain
                acc0  += e * (float)kv[rl][0];
                acc1  += e * (float)kv[rl][1];
                d_acc += e;
            }
        }
    }
    // finalize the wave's last segment
    {
        float inv = 1.0f / d_acc;
        float2 o; o.x = acc0 * inv; o.y = acc1 * inv;
        *(float2*)(out + (long)g * 128 + 2 * lane) = o;
    }
}

// ---------------------------------------------------------------------------
extern "C" void kernel_launch(void* const* d_in, const int* in_sizes, int n_in,
                              void* d_out, int out_size, void* d_ws, size_t ws_size,
                              hipStream_t stream) {
    const float* emb = (const float*)d_in[0];
    const int*   seg = (const int*)d_in[1];
    const float* Wq  = (const float*)d_in[2];
    const float* bq  = (const float*)d_in[3];
    const float* Wk  = (const float*)d_in[4];
    const float* bk  = (const float*)d_in[5];
    float* out = (float*)d_out;

    const int N = in_sizes[1];          // number of rows / seg ids
    const int G = out_size / 128;       // number of segments

    int* seg_start = (int*)d_ws;        // (G+1) ints

    seg_bounds_kernel<<<(N + 255) / 256, 256, 0, stream>>>(seg, seg_start, N, G);
    // G = 100000 divisible by 8 (8 segments per wave, 1 wave per block)
    fused_attn_kernel<<<G / 8, 64, 0, stream>>>(emb, seg_start, Wq, bq, Wk, bk, out);
}

// Round 3
// 752.788 us; speedup vs baseline: 1.1584x; 1.1432x over previous
//
#include <hip/hip_runtime.h>
#include <math.h>

typedef _Float16 half8  __attribute__((ext_vector_type(8)));
typedef _Float16 half2v __attribute__((ext_vector_type(2)));
typedef float    floatx4 __attribute__((ext_vector_type(4)));

// wave-local LDS fence: each wave only fences its OWN private LDS region
// (keys/L). DS ops complete in order per wave -> s_waitcnt lgkmcnt(0) works.
#define LGKM_FENCE() asm volatile("s_waitcnt lgkmcnt(0)" ::: "memory")

// ---------------------------------------------------------------------------
// K1: segment boundaries. seg_ids sorted, every id in [0,G) present.
// ---------------------------------------------------------------------------
__global__ void seg_bounds_kernel(const int* __restrict__ seg,
                                  int* __restrict__ seg_start, int N, int G) {
    int i = blockIdx.x * 256 + threadIdx.x;
    if (i >= N) return;
    int s = seg[i];
    if (i == 0 || s != seg[i - 1]) seg_start[s] = i;
    if (i == N - 1) seg_start[G] = N;
}

__device__ inline half8 pack8(float4 a, float4 b) {
    half8 r;
    r[0] = (_Float16)a.x; r[1] = (_Float16)a.y; r[2] = (_Float16)a.z; r[3] = (_Float16)a.w;
    r[4] = (_Float16)b.x; r[5] = (_Float16)b.y; r[6] = (_Float16)b.z; r[7] = (_Float16)b.w;
    return r;
}

// ---------------------------------------------------------------------------
// K2: fused keys-GEMM + q-GEMM + per-segment softmax + weighted sum.
// 4 WAVES PER BLOCK (256 threads); each wave owns 8 consecutive segments and
// runs the round-2 per-wave pipeline unchanged. Wk fragments are SHARED:
// staged once per block into LDS in fragment order (32 KB), read per tile
// with lane-contiguous ds_read_b128. This evicts the 128-reg wkf[][] that
// put round-2 at ~280 regs/wave (1 wave/SIMD, 11% occupancy).
// Budget: LDS 32K(wk) + 17.4K(keys x4) + 256B(L) = 50.4 KB -> 3 blocks/CU;
// launch_bounds(256,3) caps regs at 170 -> 12 waves/CU target.
// MFMA 16x16x32 f16 layouts (verified m89/m120):
//   A[m=lane&15][k=quad*8+j], B[n=lane&15][k=quad*8+j], C: col=lane&15,
//   row=quad*4+reg.
// ---------------------------------------------------------------------------
__global__ __launch_bounds__(256, 3) void fused_attn_kernel(
    const float* __restrict__ emb, const int* __restrict__ seg_start,
    const float* __restrict__ Wq, const float* __restrict__ bq,
    const float* __restrict__ Wk, const float* __restrict__ bk,
    float* __restrict__ out)
{
    __shared__ alignas(16) half8    wk_lds[8][4][64];      // 32 KB, frag order
    __shared__ alignas(16) _Float16 keys_lds[4][16][136];  // per-wave region
    __shared__ alignas(16) float    L_lds[4][16];          // per-wave region

    const int tid  = threadIdx.x;
    const int wave = tid >> 6;
    const int lane = tid & 63;
    const int m    = lane & 15;
    const int quad = lane >> 4;

    // ---- stage this wave's share of Wk fragments into LDS (c = 2w, 2w+1) --
#pragma unroll
    for (int i = 0; i < 2; ++i) {
        int c = 2 * wave + i;
        const float4* wp0 = (const float4*)(Wk + (16 * c + m) * 128 + 0 * 32 + quad * 8);
        const float4* wp1 = (const float4*)(Wk + (16 * c + m) * 128 + 1 * 32 + quad * 8);
        const float4* wp2 = (const float4*)(Wk + (16 * c + m) * 128 + 2 * 32 + quad * 8);
        const float4* wp3 = (const float4*)(Wk + (16 * c + m) * 128 + 3 * 32 + quad * 8);
        wk_lds[c][0][lane] = pack8(wp0[0], wp0[1]);
        wk_lds[c][1][lane] = pack8(wp1[0], wp1[1]);
        wk_lds[c][2][lane] = pack8(wp2[0], wp2[1]);
        wk_lds[c][3][lane] = pack8(wp3[0], wp3[1]);
    }

    const int g0 = (blockIdx.x * 4 + wave) * 8;  // this wave's 8 segments
    // per-lane bounds of "owned" segment g0+(m&7); lanes 8..15 duplicate
    const int lo = seg_start[g0 + (m & 7)];
    const int hi = seg_start[g0 + (m & 7) + 1];
    const int s0 = __shfl(lo, 0);
    const int e0 = __shfl(hi, 7);      // end of last owned segment

    // bk for this lane's column slots (dim = 16c + m)
    float bkv[8];
#pragma unroll
    for (int c = 0; c < 8; ++c) bkv[c] = bk[16 * c + m];

    // -------- phase 1: q for the 8 segments (one MFMA col pass) -----------
    // transpose through this wave's keys_lds rows 0..7 (scratch before main)
    {
        long qrow = (long)hi - 1;      // last row of owned segment (dup m>=8)
        half8 aq[4];
#pragma unroll
        for (int kq = 0; kq < 4; ++kq) {
            const float4* p = (const float4*)(emb + qrow * 128 + kq * 32 + quad * 8);
            aq[kq] = pack8(p[0], p[1]);
        }
#pragma unroll
        for (int c = 0; c < 8; ++c) {
            float bqc = bq[16 * c + m];
            floatx4 acc = {bqc, bqc, bqc, bqc};
#pragma unroll
            for (int kq = 0; kq < 4; ++kq) {
                const float4* wp = (const float4*)(Wq + (16 * c + m) * 128 + kq * 32 + quad * 8);
                half8 bf = pack8(wp[0], wp[1]);
                acc = __builtin_amdgcn_mfma_f32_16x16x32_f16(aq[kq], bf, acc, 0, 0, 0);
            }
            if (quad < 2) {                            // rows 0..7 = segments
#pragma unroll
                for (int r = 0; r < 4; ++r)
                    keys_lds[wave][quad * 4 + r][16 * c + m] = (_Float16)acc[r];
            }
        }
    }
    LGKM_FENCE();   // q rows visible to this wave

    // q as B-fragments, kept in registers for the whole main loop
    half8 qf[4];
#pragma unroll
    for (int kq = 0; kq < 4; ++kq)
        qf[kq] = *(const half8*)&keys_lds[wave][m & 7][kq * 32 + quad * 8];

    __syncthreads();   // wk_lds fully staged (all waves) before first use

    const int nt = (e0 - s0 + 15) >> 4;

    // preload tile 0 raw (software pipeline stage)
    float4 pre[8];
    {
        long prow = (long)min(s0 + m, e0 - 1);
#pragma unroll
        for (int kq = 0; kq < 4; ++kq) {
            const float4* p = (const float4*)(emb + prow * 128 + kq * 32 + quad * 8);
            pre[2 * kq] = p[0]; pre[2 * kq + 1] = p[1];
        }
    }

    // current-segment state (scalar, segments arrive sorted)
    int   g = g0;
    int   cur_end = __shfl(hi, 0);
    float M_run = -INFINITY;   // owner-lane running max for segment g0+(m&7)
    float M_cur = 0.f;         // current segment's merged max (set per tile)
    float d_acc = 0.f, acc0 = 0.f, acc1 = 0.f;

    for (int tt = 0; tt < nt; ++tt) {
        const int t   = s0 + tt * 16;
        const int cnt = min(16, e0 - t);

        // consume prefetched raw -> A fragments
        half8 ak[4];
#pragma unroll
        for (int kq = 0; kq < 4; ++kq)
            ak[kq] = pack8(pre[2 * kq], pre[2 * kq + 1]);

        // prefetch next tile (overlaps MFMA + softmax below)
        if (tt + 1 < nt) {
            long nrow = (long)min(t + 16 + m, e0 - 1);
#pragma unroll
            for (int kq = 0; kq < 4; ++kq) {
                const float4* p = (const float4*)(emb + nrow * 128 + kq * 32 + quad * 8);
                pre[2 * kq] = p[0]; pre[2 * kq + 1] = p[1];
            }
        }

        // keys = emb @ Wk^T + bk (bias folded into acc init); B from LDS
#pragma unroll
        for (int c = 0; c < 8; ++c) {
            floatx4 acc = {bkv[c], bkv[c], bkv[c], bkv[c]};
#pragma unroll
            for (int kq = 0; kq < 4; ++kq) {
                half8 bf = wk_lds[c][kq][lane];        // ds_read_b128
                acc = __builtin_amdgcn_mfma_f32_16x16x32_f16(ak[kq], bf, acc, 0, 0, 0);
            }
#pragma unroll
            for (int r = 0; r < 4; ++r)
                keys_lds[wave][quad * 4 + r][16 * c + m] = (_Float16)acc[r];
        }
        LGKM_FENCE();   // keys visible to this wave

        // logits: L[row][s] = keys[row] . q[s] via one MFMA col-tile
        floatx4 lacc = {0.f, 0.f, 0.f, 0.f};
#pragma unroll
        for (int kq = 0; kq < 4; ++kq) {
            half8 af = *(const half8*)&keys_lds[wave][m][kq * 32 + quad * 8];
            lacc = __builtin_amdgcn_mfma_f32_16x16x32_f16(af, qf[kq], lacc, 0, 0, 0);
        }
        // extract L[row][seg(row)]: the owner lane (m<8, owned range contains
        // the row) writes — exactly one lane per valid row
#pragma unroll
        for (int r = 0; r < 4; ++r) {
            int rowc = t + quad * 4 + r;
            if (m < 8 && rowc >= lo && rowc < hi) L_lds[wave][quad * 4 + r] = lacc[r];
        }
        LGKM_FENCE();   // L visible

        // batch all LDS reads, then pure register work
        float lg[16];
#pragma unroll
        for (int i = 0; i < 4; ++i) {
            float4 v = *(const float4*)&L_lds[wave][4 * i];   // broadcast reads
            lg[4 * i] = v.x; lg[4 * i + 1] = v.y; lg[4 * i + 2] = v.z; lg[4 * i + 3] = v.w;
        }
        half2v kv[16];
#pragma unroll
        for (int r = 0; r < 16; ++r)
            kv[r] = *(const half2v*)&keys_lds[wave][r][2 * lane];

        // owner-lane tile max of owned segment: masked sequential fmax chain
        // (no register array; once per tile, off the per-row path)
        float tm = -INFINITY;
#pragma unroll
        for (int r = 0; r < 16; ++r) {
            int row = t + r;
            tm = fmaxf(tm, (row >= lo && row < hi) ? lg[r] : -INFINITY);
        }
        float M_new = fmaxf(M_run, tm);
        // guard: before a segment's first row, M_run = -inf and -inf-(-inf)=NaN
        float sc = (M_run == -INFINITY) ? 0.f : __expf(M_run - M_new);
        M_run = M_new;

        // rescale current segment's accumulators once per tile
        float sc_c = __shfl(sc, g - g0);
        M_cur      = __shfl(M_new, g - g0);
        acc0 *= sc_c; acc1 *= sc_c; d_acc *= sc_c;

        // serial row phase: only independent FMA chains are loop-carried
#pragma unroll
        for (int rl = 0; rl < 16; ++rl) {
            if (rl < cnt) {                      // wave-uniform guard
                int row = t + rl;
                while (row >= cur_end) {         // wave-uniform boundary
                    float inv = 1.0f / d_acc;
                    float2 o; o.x = acc0 * inv; o.y = acc1 * inv;
                    *(float2*)(out + (long)g * 128 + 2 * lane) = o;
                    ++g;
                    cur_end = __shfl(hi, g - g0);
                    M_cur   = __shfl(M_new, g - g0);
                    acc0 = 0.f; acc1 = 0.f; d_acc = 0.f;
                }
                float e = __expf(lg[rl] - M_cur);   // off the carried chain
                acc0  += e * (float)kv[rl][0];
                acc1  += e * (float)kv[rl][1];
                d_acc += e;
            }
        }
    }
    // finalize the wave's last segment
    {
        float inv = 1.0f / d_acc;
        float2 o; o.x = acc0 * inv; o.y = acc1 * inv;
        *(float2*)(out + (long)g * 128 + 2 * lane) = o;
    }
}

// ---------------------------------------------------------------------------
extern "C" void kernel_launch(void* const* d_in, const int* in_sizes, int n_in,
                              void* d_out, int out_size, void* d_ws, size_t ws_size,
                              hipStream_t stream) {
    const float* emb = (const float*)d_in[0];
    const int*   seg = (const int*)d_in[1];
    const float* Wq  = (const float*)d_in[2];
    const float* bq  = (const float*)d_in[3];
    const float* Wk  = (const float*)d_in[4];
    const float* bk  = (const float*)d_in[5];
    float* out = (float*)d_out;

    const int N = in_sizes[1];          // number of rows / seg ids
    const int G = out_size / 128;       // number of segments

    int* seg_start = (int*)d_ws;        // (G+1) ints

    seg_bounds_kernel<<<(N + 255) / 256, 256, 0, stream>>>(seg, seg_start, N, G);
    // G = 100000 divisible by 32 (4 waves x 8 segments per block)
    fused_attn_kernel<<<G / 32, 256, 0, stream>>>(emb, seg_start, Wq, bq, Wk, bk, out);
}